// Round 4
// baseline (575.545 us; speedup 1.0000x reference)
//
#include <hip/hip_runtime.h>
#include <stdint.h>

typedef unsigned int u32;
typedef unsigned long long u64;

// Monotone bijection float -> u32 (order-preserving for all non-NaN floats).
// ord==0 only for negative-NaN, so 0 is a safe "empty segment" marker.
__device__ __forceinline__ u32 f2o(float f) {
    u32 u = __float_as_uint(f);
    return (u & 0x80000000u) ? ~u : (u | 0x80000000u);
}
__device__ __forceinline__ float o2f(u32 u) {
    return __uint_as_float((u & 0x80000000u) ? (u & 0x7fffffffu) : ~u);
}

#define TJ 64

// ===========================================================================
// Sort-based path (C == 64): no global atomics, no 256MB memset.
//   A: transpose src -> src_t[j][c] (+ histogram & per-element slot)
//   B1/B2/B3: exclusive scan of the 500K-bucket histogram
//   C: counting-sort scatter of j by segment
//   D: per-64-segment tile: register segment-reduce + fused finalize
// ===========================================================================

// A: LDS-tiled transpose + histogram.
__global__ __launch_bounds__(256) void transpose_hist_kernel(
        const float* __restrict__ src, const int* __restrict__ index,
        float* __restrict__ srct, u32* __restrict__ count, u32* __restrict__ pos,
        int N, int vec_ok) {
    __shared__ float tile[64 * 65];
    __shared__ int idx[TJ];
    const int j0 = blockIdx.x * TJ;
    const int t = threadIdx.x;
    const int nj = min(TJ, N - j0);

    if (t < nj) idx[t] = index[j0 + t];

    if (nj == TJ && vec_ok) {
        const int r0 = t >> 4, q = t & 15;
        #pragma unroll
        for (int p = 0; p < 4; ++p) {
            const int c = r0 + p * 16;
            float4 v = *reinterpret_cast<const float4*>(src + (size_t)c * N + j0 + q * 4);
            float* d = &tile[c * 65 + q * 4];
            d[0] = v.x; d[1] = v.y; d[2] = v.z; d[3] = v.w;
        }
    } else {
        for (int e = t; e < 64 * TJ; e += 256) {
            const int c = e >> 6, jj = e & 63;
            tile[c * 65 + jj] = (jj < nj) ? src[(size_t)c * N + j0 + jj] : 0.0f;
        }
    }
    __syncthreads();

    if (t < nj) pos[j0 + t] = atomicAdd(&count[idx[t]], 1u);

    const int lane = t & 63, w = t >> 6;
    #pragma unroll 4
    for (int jj = w; jj < nj; jj += 4) {
        srct[(size_t)(j0 + jj) * 64 + lane] = tile[lane * 65 + jj];  // 256B/wave-op
    }
}

// B1: per-1024-element block sums of count.
__global__ __launch_bounds__(256) void scan_bsum_kernel(
        const u32* __restrict__ count, u32* __restrict__ bsum, int N) {
    __shared__ u32 s[256];
    const int b = blockIdx.x, t = threadIdx.x;
    const int base = b * 1024 + t * 4;
    u32 a = 0;
    if (base + 3 < N) {
        uint4 v = *reinterpret_cast<const uint4*>(count + base);
        a = v.x + v.y + v.z + v.w;
    } else {
        for (int i = 0; i < 4; ++i) if (base + i < N) a += count[base + i];
    }
    s[t] = a; __syncthreads();
    for (int off = 128; off > 0; off >>= 1) {
        if (t < off) s[t] += s[t + off];
        __syncthreads();
    }
    if (t == 0) bsum[b] = s[0];
}

// B2: single-block exclusive scan of up to 1024 block sums.
__global__ __launch_bounds__(1024) void scan_top_kernel(
        const u32* __restrict__ bsum, u32* __restrict__ boffs, int NB) {
    __shared__ u32 s[1024];
    const int t = threadIdx.x;
    const u32 v = (t < NB) ? bsum[t] : 0u;
    s[t] = v; __syncthreads();
    for (int off = 1; off < 1024; off <<= 1) {
        u32 x = (t >= off) ? s[t - off] : 0u;
        __syncthreads();
        s[t] += x;
        __syncthreads();
    }
    if (t < NB) boffs[t] = s[t] - v;
}

// B3: per-block exclusive scan + block offset -> offs[].
__global__ __launch_bounds__(256) void scan_final_kernel(
        const u32* __restrict__ count, const u32* __restrict__ boffs,
        u32* __restrict__ offs, int N) {
    __shared__ u32 s[256];
    const int b = blockIdx.x, t = threadIdx.x;
    const int base = b * 1024 + t * 4;
    u32 a0 = 0, a1 = 0, a2 = 0, a3 = 0;
    if (base + 3 < N) {
        uint4 v = *reinterpret_cast<const uint4*>(count + base);
        a0 = v.x; a1 = v.y; a2 = v.z; a3 = v.w;
    } else {
        if (base < N)     a0 = count[base];
        if (base + 1 < N) a1 = count[base + 1];
        if (base + 2 < N) a2 = count[base + 2];
        if (base + 3 < N) a3 = count[base + 3];
    }
    const u32 ts = a0 + a1 + a2 + a3;
    s[t] = ts; __syncthreads();
    for (int off = 1; off < 256; off <<= 1) {
        u32 x = (t >= off) ? s[t - off] : 0u;
        __syncthreads();
        s[t] += x;
        __syncthreads();
    }
    u32 run = boffs[b] + s[t] - ts;
    if (base < N)     offs[base] = run;     run += a0;
    if (base + 1 < N) offs[base + 1] = run; run += a1;
    if (base + 2 < N) offs[base + 2] = run; run += a2;
    if (base + 3 < N) offs[base + 3] = run;
}

// C: counting-sort scatter (order within a segment is irrelevant: the reduce
// tracks j explicitly and ties resolve by min-j via the packed compare).
__global__ __launch_bounds__(256) void sort_scatter_kernel(
        const int* __restrict__ index, const u32* __restrict__ pos,
        const u32* __restrict__ offs, u32* __restrict__ sortedj, int N) {
    const int j = blockIdx.x * 256 + threadIdx.x;
    if (j < N) {
        const int k = index[j];
        sortedj[offs[k] + pos[j]] = (u32)j;
    }
}

// D: fused segment-reduce + finalize for 64 segments per block.
__global__ __launch_bounds__(256) void segreduce_finalize_kernel(
        const float* __restrict__ src, const float* __restrict__ srct,
        const u32* __restrict__ sortedj, const u32* __restrict__ offs,
        float* __restrict__ outv, float* __restrict__ outa, int N, u32 NV) {
    __shared__ u32 lord[64 * 65];
    __shared__ u32 larg[64 * 65];
    __shared__ u32 loffs[65];
    const int k0 = blockIdx.x * 64;
    const int t = threadIdx.x;
    const int nk = min(64, N - k0);
    if (t < 65) {
        const int ik = k0 + t;
        loffs[t] = (ik < N) ? offs[ik] : (u32)N;
    }
    __syncthreads();

    const int lane = t & 63, w = t >> 6;

    // Phase A: wave w owns segments [w*16, w*16+16); lane = channel.
    for (int kk = w * 16; kk < w * 16 + 16; ++kk) {
        if (kk >= nk) break;
        const u32 s = loffs[kk], e = loffs[kk + 1];
        u64 pm = 0ull;
        for (u32 x = s; x < e; ++x) {
            const u32 jj = sortedj[x];                       // uniform -> broadcast
            const float v = srct[(size_t)jj * 64 + lane];    // 256B coalesced
            const u64 p = ((u64)f2o(v) << 32) | (u32)(~jj);
            pm = pm > p ? pm : p;
        }
        lord[kk * 65 + lane] = (u32)(pm >> 32);
        larg[kk * 65 + lane] = ~(u32)pm;
    }
    __syncthreads();

    // Phase B: vectorized row-major finalize (thread owns (c, 4 consecutive k)).
    const int q = lane & 15, cg = lane >> 4;
    const int kq = q * 4;
    #pragma unroll
    for (int p = 0; p < 4; ++p) {
        const int c = p * 16 + w * 4 + cg;
        const size_t off = (size_t)c * N + k0 + kq;
        if (kq + 3 < nk) {
            float4 sv4 = *reinterpret_cast<const float4*>(src + off);
            float sv[4] = {sv4.x, sv4.y, sv4.z, sv4.w};
            float4 ov, av;
            float* po = &ov.x; float* pa = &av.x;
            #pragma unroll
            for (int i = 0; i < 4; ++i) {
                const u32 ord = lord[(kq + i) * 65 + c];
                float o, a;
                if (ord == 0u) { o = sv[i]; a = (float)NV; }
                else {
                    const float m = o2f(ord);
                    o = fmaxf(sv[i], m);
                    a = (m >= sv[i]) ? (float)larg[(kq + i) * 65 + c] : (float)NV;
                }
                po[i] = o; pa[i] = a;
            }
            *reinterpret_cast<float4*>(outv + off) = ov;
            *reinterpret_cast<float4*>(outa + off) = av;
        } else {
            for (int i = 0; i < 4 && kq + i < nk; ++i) {
                const float s = src[off + i];
                const u32 ord = lord[(kq + i) * 65 + c];
                float o, a;
                if (ord == 0u) { o = s; a = (float)NV; }
                else {
                    const float m = o2f(ord);
                    o = fmaxf(s, m);
                    a = (m >= s) ? (float)larg[(kq + i) * 65 + c] : (float)NV;
                }
                outv[off + i] = o;
                outa[off + i] = a;
            }
        }
    }
}

// ===========================================================================
// Fallback: round-3 transposed-atomic path (C == 64) and generic path.
// ===========================================================================
__global__ __launch_bounds__(256) void scatter_tr_kernel(
        const float* __restrict__ src, const int* __restrict__ index,
        u64* __restrict__ packt, int N, int vec_ok) {
    __shared__ float tile[64 * 65];
    __shared__ int idx[TJ];
    const int j0 = blockIdx.x * TJ;
    const int t = threadIdx.x;
    const int nj = min(TJ, N - j0);
    if (t < nj) idx[t] = index[j0 + t];
    if (nj == TJ && vec_ok) {
        const int r0 = t >> 4, q = t & 15;
        #pragma unroll
        for (int p = 0; p < 4; ++p) {
            const int c = r0 + p * 16;
            float4 v = *reinterpret_cast<const float4*>(src + (size_t)c * N + j0 + q * 4);
            float* d = &tile[c * 65 + q * 4];
            d[0] = v.x; d[1] = v.y; d[2] = v.z; d[3] = v.w;
        }
    } else {
        for (int e = t; e < 64 * TJ; e += 256) {
            const int c = e >> 6, jj = e & 63;
            tile[c * 65 + jj] = (jj < nj) ? src[(size_t)c * N + j0 + jj] : 0.0f;
        }
    }
    __syncthreads();
    const int lane = t & 63, w = t >> 6;
    #pragma unroll 4
    for (int jj = w; jj < nj; jj += 4) {
        const int j = j0 + jj;
        const u32 k = (u32)idx[jj];
        const float v = tile[lane * 65 + jj];
        const u64 p = ((u64)f2o(v) << 32) | (u32)(~(u32)j);
        atomicMax(&packt[(size_t)k * 64 + lane], p);
    }
}

__global__ __launch_bounds__(256) void finalize_tr_kernel(
        const float* __restrict__ src, const u64* __restrict__ packt,
        float* __restrict__ outv, float* __restrict__ outa, int N, u32 NV) {
    __shared__ u32 lord[64 * 65];
    __shared__ u32 larg[64 * 65];
    const int k0 = blockIdx.x * 64;
    const int t = threadIdx.x;
    const int nk = min(64, N - k0);
    {
        const u64* base = packt + (size_t)k0 * 64;
        const int npairs = nk * 32;
        #pragma unroll
        for (int v = 0; v < 8; ++v) {
            const int i2 = t + v * 256;
            if (i2 < npairs) {
                const int e = i2 * 2;
                ulonglong2 p = *reinterpret_cast<const ulonglong2*>(base + e);
                const int kk = e >> 6, c = e & 63;
                lord[kk * 65 + c]     = (u32)(p.x >> 32);
                larg[kk * 65 + c]     = ~(u32)p.x;
                lord[kk * 65 + c + 1] = (u32)(p.y >> 32);
                larg[kk * 65 + c + 1] = ~(u32)p.y;
            }
        }
    }
    __syncthreads();
    const int lane = t & 63, w = t >> 6;
    const int q = lane & 15, cg = lane >> 4;
    const int kq = q * 4;
    #pragma unroll
    for (int p = 0; p < 4; ++p) {
        const int c = p * 16 + w * 4 + cg;
        const size_t off = (size_t)c * N + k0 + kq;
        if (kq + 3 < nk) {
            float4 s = *reinterpret_cast<const float4*>(src + off);
            float sv[4] = {s.x, s.y, s.z, s.w};
            float4 ov, av;
            float* po = &ov.x; float* pa = &av.x;
            #pragma unroll
            for (int i = 0; i < 4; ++i) {
                const u32 ord = lord[(kq + i) * 65 + c];
                float o, a;
                if (ord == 0u) { o = sv[i]; a = (float)NV; }
                else {
                    const float m = o2f(ord);
                    o = fmaxf(sv[i], m);
                    a = (m >= sv[i]) ? (float)larg[(kq + i) * 65 + c] : (float)NV;
                }
                po[i] = o; pa[i] = a;
            }
            *reinterpret_cast<float4*>(outv + off) = ov;
            *reinterpret_cast<float4*>(outa + off) = av;
        } else {
            for (int i = 0; i < 4 && kq + i < nk; ++i) {
                const float s = src[off + i];
                const u32 ord = lord[(kq + i) * 65 + c];
                float o, a;
                if (ord == 0u) { o = s; a = (float)NV; }
                else {
                    const float m = o2f(ord);
                    o = fmaxf(s, m);
                    a = (m >= s) ? (float)larg[(kq + i) * 65 + c] : (float)NV;
                }
                outv[off + i] = o;
                outa[off + i] = a;
            }
        }
    }
}

__global__ void scatter_pack_kernel(const float* __restrict__ src,
                                    const int* __restrict__ index,
                                    u64* __restrict__ pack, int N) {
    const int c = blockIdx.y;
    const int j0 = (blockIdx.x * blockDim.x + threadIdx.x) * 4;
    const float* srow = src + (size_t)c * N;
    u64* prow = pack + (size_t)c * N;
    if (j0 + 3 < N) {
        float4 v = *reinterpret_cast<const float4*>(srow + j0);
        int4 k = *reinterpret_cast<const int4*>(index + j0);
        atomicMax(&prow[k.x], ((u64)f2o(v.x) << 32) | (u32)(~(u32)(j0 + 0)));
        atomicMax(&prow[k.y], ((u64)f2o(v.y) << 32) | (u32)(~(u32)(j0 + 1)));
        atomicMax(&prow[k.z], ((u64)f2o(v.z) << 32) | (u32)(~(u32)(j0 + 2)));
        atomicMax(&prow[k.w], ((u64)f2o(v.w) << 32) | (u32)(~(u32)(j0 + 3)));
    } else {
        for (int j = j0; j < N; ++j)
            atomicMax(&prow[index[j]], ((u64)f2o(srow[j]) << 32) | (u32)(~(u32)j));
    }
}

__global__ void finalize_pack_kernel(const float* __restrict__ src,
                                     const u64* __restrict__ pack,
                                     float* __restrict__ outv,
                                     float* __restrict__ outa,
                                     size_t total, u32 NV) {
    size_t i = (size_t)blockIdx.x * blockDim.x + threadIdx.x;
    const size_t stride = (size_t)gridDim.x * blockDim.x;
    for (; i < total; i += stride) {
        const float s = src[i];
        const u64 p = pack[i];
        const u32 ord = (u32)(p >> 32);
        float o, a;
        if (ord == 0u) { o = s; a = (float)NV; }
        else {
            const float m = o2f(ord);
            o = fmaxf(s, m);
            a = (m >= s) ? (float)(~(u32)p) : (float)NV;
        }
        outv[i] = o;
        outa[i] = a;
    }
}

extern "C" void kernel_launch(void* const* d_in, const int* in_sizes, int n_in,
                              void* d_out, int out_size, void* d_ws, size_t ws_size,
                              hipStream_t stream) {
    const float* src = (const float*)d_in[0];
    const int* index = (const int*)d_in[1];
    const int N = in_sizes[1];
    const int C = in_sizes[0] / N;
    const size_t total = (size_t)C * N;
    float* out = (float*)d_out;

    const int NB = (N + 1023) / 1024;
    // ws layout for sort path: src_t | count | pos | offs | sortedj | bsum | boffs
    float* srct   = (float*)d_ws;
    u32* count    = (u32*)((char*)d_ws + total * sizeof(float));
    u32* pos      = count + N;
    u32* offsa    = pos + N;
    u32* sortedj  = offsa + N;
    u32* bsum     = sortedj + N;
    u32* boffs    = bsum + 1024;
    const size_t need = total * sizeof(float) + (size_t)N * 4 * sizeof(u32) + 2048 * sizeof(u32);

    const int nblk = (N + TJ - 1) / TJ;
    const int vec_ok = ((N & 3) == 0);

    if (C == 64 && NB <= 1024 && ws_size >= need) {
        hipMemsetAsync(count, 0, (size_t)N * sizeof(u32), stream);
        transpose_hist_kernel<<<nblk, 256, 0, stream>>>(src, index, srct, count, pos,
                                                        N, vec_ok);
        scan_bsum_kernel<<<NB, 256, 0, stream>>>(count, bsum, N);
        scan_top_kernel<<<1, 1024, 0, stream>>>(bsum, boffs, NB);
        scan_final_kernel<<<NB, 256, 0, stream>>>(count, boffs, offsa, N);
        sort_scatter_kernel<<<(N + 255) / 256, 256, 0, stream>>>(index, pos, offsa,
                                                                 sortedj, N);
        segreduce_finalize_kernel<<<nblk, 256, 0, stream>>>(src, srct, sortedj, offsa,
                                                            out, out + total, N, (u32)N);
    } else if (C == 64 && ws_size >= total * sizeof(u64)) {
        u64* pack = (u64*)d_ws;
        hipMemsetAsync(pack, 0, total * sizeof(u64), stream);
        scatter_tr_kernel<<<nblk, 256, 0, stream>>>(src, index, pack, N, vec_ok);
        finalize_tr_kernel<<<nblk, 256, 0, stream>>>(src, pack, out, out + total,
                                                     N, (u32)N);
    } else {
        u64* pack = (u64*)d_ws;
        hipMemsetAsync(pack, 0, total * sizeof(u64), stream);
        const int TPB = 256;
        dim3 sg((N + TPB * 4 - 1) / (TPB * 4), C);
        scatter_pack_kernel<<<sg, TPB, 0, stream>>>(src, index, pack, N);
        finalize_pack_kernel<<<2048, TPB, 0, stream>>>(src, pack, out, out + total,
                                                       total, (u32)N);
    }
}